// Round 11
// baseline (147.745 us; speedup 1.0000x reference)
//
#include <hip/hip_runtime.h>

typedef __fp16   cvt16x2 __attribute__((ext_vector_type(2)));
typedef _Float16 h2      __attribute__((ext_vector_type(2)));
typedef _Float16 half4_t __attribute__((ext_vector_type(4)));
typedef unsigned uint2v  __attribute__((ext_vector_type(2)));
typedef float    f32x4   __attribute__((ext_vector_type(4)));

#define CH 8   // 64-sample chunks per wave; 128-thread block => 1024 samples
#define LOG2E 1.44269504f
#define LN2   0.69314718f

__device__ __forceinline__ unsigned pk(float a, float b) {
    cvt16x2 h = __builtin_amdgcn_cvt_pkrtz(a, b);
    return __builtin_bit_cast(unsigned, h);
}
__device__ __forceinline__ half4_t mkfrag(unsigned lo, unsigned hi) {
    uint2v u; u[0] = lo; u[1] = hi;
    return __builtin_bit_cast(half4_t, u);
}

// Scaled-domain ELU with POLYNOMIAL exp2 (no trans ops).
// Input v' = v*log2e; output H' = max(v', lg*2^t - lg), t = min(v',0).
// 2^t computed as (P(t/4)^2)^2 with P = degree-4 Chebyshev fit of 2^s on
// [-2,0] (exact at s = 0,-1,-2); t clamped at -8 (residual err 2^-8).
// All ops are packed v_pk_* f16 -> moves ELU off the quarter-rate trans pipe.
__device__ __forceinline__ unsigned elu_pk(float a, float b) {
    h2 v = __builtin_bit_cast(h2, __builtin_amdgcn_cvt_pkrtz(a, b));
    const h2 z    = {(_Float16)0.f,        (_Float16)0.f};
    const h2 quar = {(_Float16)0.25f,      (_Float16)0.25f};
    const h2 mtwo = {(_Float16)(-2.f),     (_Float16)(-2.f)};
    const h2 c0   = {(_Float16)0.999905f,  (_Float16)0.999905f};
    const h2 c1   = {(_Float16)0.691885f,  (_Float16)0.691885f};
    const h2 c2   = {(_Float16)0.235320f,  (_Float16)0.235320f};
    const h2 c3   = {(_Float16)0.048260f,  (_Float16)0.048260f};
    const h2 c4   = {(_Float16)0.004920f,  (_Float16)0.004920f};
    const h2 lg   = {(_Float16)LOG2E,      (_Float16)LOG2E};
    const h2 mlg  = {(_Float16)(-LOG2E),   (_Float16)(-LOG2E)};
    h2 t = __builtin_elementwise_min(v, z);
    h2 s = __builtin_elementwise_max(t * quar, mtwo);   // s = clamp(t/4, -2, 0)
    h2 q = s * c4 + c3;                                 // Horner (v_pk_fma_f16)
    q = q * s + c2;
    q = q * s + c1;
    q = q * s + c0;                                     // ~2^s
    q = q * q;
    q = q * q;                                          // 2^t
    h2 r = __builtin_elementwise_max(v, q * lg + mlg);
    return __builtin_bit_cast(unsigned, r);
}

// No LDS, no barriers, no shuffles, no masks. Per sub-batch of 16 samples:
// z-MFMA -> sincos -> 3 L1 MFMAs -> 3x(ELU+MFMA) -> ELU+head MFMA -> store.
// Accumulators live in the log2e-scaled domain; A2..A4 unchanged
// (log2e*ln2 == 1), A5 carries ln2 un-scaling, b5 rides in head C-in.
__global__ __launch_bounds__(128, 4) void pixenc_mfma9(
    const float* __restrict__ x,
    const float* __restrict__ Bl,
    const float* __restrict__ W1, const float* __restrict__ b1,
    const float* __restrict__ W2, const float* __restrict__ b2,
    const float* __restrict__ W3, const float* __restrict__ b3,
    const float* __restrict__ W4, const float* __restrict__ b4,
    const float* __restrict__ W5, const float* __restrict__ b5,
    float* __restrict__ out)
{
    const int t    = threadIdx.x;
    const int lane = t & 63;
    const int w    = t >> 6;
    const int g    = lane >> 4;
    const int m    = lane & 15;

    // ---- per-lane weight fragments; A1/c1..c4 pre-scaled by log2e ----
    half4_t A1[3], A2, A3, A4;
    #pragma unroll
    for (int e = 0; e < 4; ++e) {
        const int c0 = 4 * e + g;                 // layer-1 slot (g,e) -> x col
        A1[0][e] = (c0 < 9) ? (_Float16)(W1[c0 * 16 + m] * LOG2E) : (_Float16)0.f;
        A1[1][e] = (_Float16)(W1[(9  + g * 4 + e) * 16 + m] * LOG2E);
        A1[2][e] = (_Float16)(W1[(25 + g * 4 + e) * 16 + m] * LOG2E);
        A2[e]    = (_Float16)W2[(g * 4 + e) * 16 + m];
        A3[e]    = (_Float16)W3[(g * 4 + e) * 16 + m];
        A4[e]    = (_Float16)W4[(g * 4 + e) * 16 + m];
    }
    // z-MFMA A: row f: k0 -> Bl_row0[f], k1 -> Bl_row1[f]; zero cols k>=2.
    const half4_t Az = (g == 0) ? mkfrag(pk(Bl[m], Bl[16 + m]), 0u)
                                : mkfrag(0u, 0u);
    // head A: row 0 = W5 * ln2 (un-scales H4' = log2e*H4)
    const half4_t A5 = (m == 0)
        ? mkfrag(pk(W5[g * 4 + 0] * LN2, W5[g * 4 + 1] * LN2),
                 pk(W5[g * 4 + 2] * LN2, W5[g * 4 + 3] * LN2))
        : mkfrag(0u, 0u);
    f32x4 c1, c2, c3, c4;
    #pragma unroll
    for (int e = 0; e < 4; ++e) {
        const int r = g * 4 + e;
        c1[e] = b1[r] * LOG2E; c2[e] = b2[r] * LOG2E;
        c3[e] = b3[r] * LOG2E; c4[e] = b4[r] * LOG2E;
    }
    const f32x4 zero4 = {0.f, 0.f, 0.f, 0.f};
    f32x4 c5 = zero4;
    if (g == 0) c5[0] = b5[0];                    // b5 via head C-in row 0

    const int wavebase = blockIdx.x * (128 * CH) + w * (64 * CH);

    // per-lane base pointers; all loop loads use compile-time offsets
    const float* aA = x + (size_t)(wavebase + m) * 11 + g;   // cols g, 4+g
    const float* aB = x + (size_t)(wavebase + m) * 11 + 8;   // cols 8,9,10
    float* outp = out + wavebase + m;

    // ---- prologue: load+pack chunk 0 ----
    unsigned cp0[4], cp8[4], cbz[4];
    #pragma unroll
    for (int s = 0; s < 4; ++s) {
        const float a0 = aA[s * 176], a1 = aA[s * 176 + 4];
        const float b8 = aB[s * 176], b9 = aB[s * 176 + 1], b10 = aB[s * 176 + 2];
        cp0[s] = pk(a0, a1); cp8[s] = pk(b8, 0.f);
        cbz[s] = pk(b9, b10);          // garbage B-rows k>=4 hit zero A cols
    }

    #pragma unroll
    for (int c = 0; c < CH; ++c) {
        // ---- prefetch chunk c+1 (advance pointers, immediate offsets) ----
        unsigned np0[4], np8[4], nbz[4];
        if (c + 1 < CH) {
            aA += 704; aB += 704;                 // 64 samples * 11 floats
            #pragma unroll
            for (int s = 0; s < 4; ++s) {
                const float a0 = aA[s * 176], a1 = aA[s * 176 + 4];
                const float b8 = aB[s * 176], b9 = aB[s * 176 + 1], b10 = aB[s * 176 + 2];
                np0[s] = pk(a0, a1); np8[s] = pk(b8, 0.f);
                nbz[s] = pk(b9, b10);
            }
        }

        // ---- z-MFMAs for all 4 sub-batches (independent, pipelined) ----
        f32x4 az[4];
        #pragma unroll
        for (int s = 0; s < 4; ++s)
            az[s] = __builtin_amdgcn_mfma_f32_16x16x16f16(
                        Az, mkfrag(cbz[s], 0u), zero4, 0, 0, 0);

        // ---- layer 1: trans + fragment build + 3-MFMA chain per s ----
        f32x4 acc[4];
        #pragma unroll
        for (int s = 0; s < 4; ++s) {
            float cs[4], sn[4];
            #pragma unroll
            for (int e = 0; e < 4; ++e) {
                const float zf = __builtin_amdgcn_fractf(az[s][e]);
                cs[e] = __builtin_amdgcn_cosf(zf);
                sn[e] = __builtin_amdgcn_sinf(zf);
            }
            const half4_t F0 = mkfrag(cp0[s], cp8[s]);
            const half4_t F1 = mkfrag(pk(cs[0], cs[1]), pk(cs[2], cs[3]));
            const half4_t F2 = mkfrag(pk(sn[0], sn[1]), pk(sn[2], sn[3]));
            f32x4 a = c1;
            a = __builtin_amdgcn_mfma_f32_16x16x16f16(A1[0], F0, a, 0, 0, 0);
            a = __builtin_amdgcn_mfma_f32_16x16x16f16(A1[1], F1, a, 0, 0, 0);
            a = __builtin_amdgcn_mfma_f32_16x16x16f16(A1[2], F2, a, 0, 0, 0);
            acc[s] = a;
        }

        // ---- layers 2-4: 4 independent chains, interleaved ----
        half4_t H[4];
        #pragma unroll
        for (int s = 0; s < 4; ++s)
            H[s] = mkfrag(elu_pk(acc[s][0], acc[s][1]), elu_pk(acc[s][2], acc[s][3]));
        #pragma unroll
        for (int s = 0; s < 4; ++s)
            acc[s] = __builtin_amdgcn_mfma_f32_16x16x16f16(A2, H[s], c2, 0, 0, 0);

        #pragma unroll
        for (int s = 0; s < 4; ++s)
            H[s] = mkfrag(elu_pk(acc[s][0], acc[s][1]), elu_pk(acc[s][2], acc[s][3]));
        #pragma unroll
        for (int s = 0; s < 4; ++s)
            acc[s] = __builtin_amdgcn_mfma_f32_16x16x16f16(A3, H[s], c3, 0, 0, 0);

        #pragma unroll
        for (int s = 0; s < 4; ++s)
            H[s] = mkfrag(elu_pk(acc[s][0], acc[s][1]), elu_pk(acc[s][2], acc[s][3]));
        #pragma unroll
        for (int s = 0; s < 4; ++s)
            acc[s] = __builtin_amdgcn_mfma_f32_16x16x16f16(A4, H[s], c4, 0, 0, 0);

        // ---- head: ELU + head-MFMA (b5 in C); row 0 = outputs; store ----
        #pragma unroll
        for (int s = 0; s < 4; ++s)
            H[s] = mkfrag(elu_pk(acc[s][0], acc[s][1]), elu_pk(acc[s][2], acc[s][3]));
        #pragma unroll
        for (int s = 0; s < 4; ++s) {
            const f32x4 oh = __builtin_amdgcn_mfma_f32_16x16x16f16(
                                 A5, H[s], c5, 0, 0, 0);
            if (g == 0) outp[c * 64 + s * 16] = oh[0];
        }

        // ---- rotate prefetch ----
        if (c + 1 < CH) {
            #pragma unroll
            for (int s = 0; s < 4; ++s) {
                cp0[s] = np0[s]; cp8[s] = np8[s]; cbz[s] = nbz[s];
            }
        }
    }
}

// Guarded scalar tail (only launched when N % 1024 != 0; never for N=8388608).
__global__ void pixenc_tail(
    const float* __restrict__ x, const float* __restrict__ Bl,
    const float* __restrict__ W1, const float* __restrict__ b1,
    const float* __restrict__ W2, const float* __restrict__ b2,
    const float* __restrict__ W3, const float* __restrict__ b3,
    const float* __restrict__ W4, const float* __restrict__ b4,
    const float* __restrict__ W5, const float* __restrict__ b5,
    float* __restrict__ out, int N, int start)
{
    const int i = start + blockIdx.x * 256 + threadIdx.x;
    if (i >= N) return;
    const float* xr = x + (size_t)i * 11;
    float feats[41];
    for (int k = 0; k < 9; ++k) feats[k] = xr[k];
    for (int f = 0; f < 16; ++f) {
        const float ang = 6.283185f * (xr[9] * Bl[f] + xr[10] * Bl[16 + f]);
        float s, c; __sincosf(ang, &s, &c);
        feats[9 + f] = c; feats[25 + f] = s;
    }
    float h[16], gg[16];
    for (int j = 0; j < 16; ++j) h[j] = b1[j];
    for (int k = 0; k < 41; ++k)
        for (int j = 0; j < 16; ++j) h[j] = fmaf(feats[k], W1[k * 16 + j], h[j]);
    for (int j = 0; j < 16; ++j) h[j] = h[j] > 0.f ? h[j] : __expf(h[j]) - 1.f;
    for (int j = 0; j < 16; ++j) gg[j] = b2[j];
    for (int k = 0; k < 16; ++k)
        for (int j = 0; j < 16; ++j) gg[j] = fmaf(h[k], W2[k * 16 + j], gg[j]);
    for (int j = 0; j < 16; ++j) gg[j] = gg[j] > 0.f ? gg[j] : __expf(gg[j]) - 1.f;
    for (int j = 0; j < 16; ++j) h[j] = b3[j];
    for (int k = 0; k < 16; ++k)
        for (int j = 0; j < 16; ++j) h[j] = fmaf(gg[k], W3[k * 16 + j], h[j]);
    for (int j = 0; j < 16; ++j) h[j] = h[j] > 0.f ? h[j] : __expf(h[j]) - 1.f;
    for (int j = 0; j < 16; ++j) gg[j] = b4[j];
    for (int k = 0; k < 16; ++k)
        for (int j = 0; j < 16; ++j) gg[j] = fmaf(h[k], W4[k * 16 + j], gg[j]);
    for (int j = 0; j < 16; ++j) gg[j] = gg[j] > 0.f ? gg[j] : __expf(gg[j]) - 1.f;
    float o = b5[0];
    for (int j = 0; j < 16; ++j) o = fmaf(gg[j], W5[j], o);
    out[i] = o;
}

extern "C" void kernel_launch(void* const* d_in, const int* in_sizes, int n_in,
                              void* d_out, int out_size, void* d_ws, size_t ws_size,
                              hipStream_t stream) {
    const float* x  = (const float*)d_in[0];
    const float* Bl = (const float*)d_in[1];
    const float* W1 = (const float*)d_in[2];
    const float* b1 = (const float*)d_in[3];
    const float* W2 = (const float*)d_in[4];
    const float* b2 = (const float*)d_in[5];
    const float* W3 = (const float*)d_in[6];
    const float* b3 = (const float*)d_in[7];
    const float* W4 = (const float*)d_in[8];
    const float* b4 = (const float*)d_in[9];
    const float* W5 = (const float*)d_in[10];
    const float* b5 = (const float*)d_in[11];
    float* out = (float*)d_out;

    const int N = out_size;
    const int NB = N / (128 * CH);
    const int rem = N - NB * (128 * CH);
    if (NB > 0)
        pixenc_mfma9<<<NB, 128, 0, stream>>>(x, Bl, W1, b1, W2, b2, W3, b3,
                                             W4, b4, W5, b5, out);
    if (rem > 0)
        pixenc_tail<<<(rem + 255) / 256, 256, 0, stream>>>(
            x, Bl, W1, b1, W2, b2, W3, b3, W4, b4, W5, b5, out, N, NB * 128 * CH);
}

// Round 12
// 126.835 us; speedup vs baseline: 1.1649x; 1.1649x over previous
//
#include <hip/hip_runtime.h>

typedef __fp16   cvt16x2 __attribute__((ext_vector_type(2)));
typedef _Float16 h2      __attribute__((ext_vector_type(2)));
typedef _Float16 half4_t __attribute__((ext_vector_type(4)));
typedef unsigned uint2v  __attribute__((ext_vector_type(2)));
typedef float    f32x4   __attribute__((ext_vector_type(4)));

#define CH 8   // 64-sample chunks per wave; 128-thread block => 1024 samples
#define LOG2E 1.44269504f
#define LN2   0.69314718f

#if !__has_builtin(__builtin_elementwise_exp2)
extern "C" __device__ _Float16 __ocml_exp2_f16(_Float16);
#endif

__device__ __forceinline__ unsigned pk(float a, float b) {
    cvt16x2 h = __builtin_amdgcn_cvt_pkrtz(a, b);
    return __builtin_bit_cast(unsigned, h);
}
__device__ __forceinline__ half4_t mkfrag(unsigned lo, unsigned hi) {
    uint2v u; u[0] = lo; u[1] = hi;
    return __builtin_bit_cast(half4_t, u);
}

// Scaled-domain ELU (R9 form — hardware v_exp_f16; R10's polynomial version
// regressed: trans is free, VALU issue count is the binding currency).
// Input v' = v*log2e; output H' = max(v', exp2(min(v',0))*lg - lg).
__device__ __forceinline__ unsigned elu_pk(float a, float b) {
    h2 v = __builtin_bit_cast(h2, __builtin_amdgcn_cvt_pkrtz(a, b));
    const h2 z   = {(_Float16)0.f, (_Float16)0.f};
    const h2 lg  = {(_Float16)LOG2E, (_Float16)LOG2E};
    const h2 mlg = {(_Float16)(-LOG2E), (_Float16)(-LOG2E)};
    h2 t = __builtin_elementwise_min(v, z);
#if __has_builtin(__builtin_elementwise_exp2)
    h2 ev = __builtin_elementwise_exp2(t);
#else
    h2 ev; ev[0] = __ocml_exp2_f16(t[0]); ev[1] = __ocml_exp2_f16(t[1]);
#endif
    h2 r = __builtin_elementwise_max(v, ev * lg + mlg);   // v_pk_fma_f16
    return __builtin_bit_cast(unsigned, r);
}

// No LDS, no barriers, no shuffles, no masks. Per sub-batch of 16 samples:
// z-MFMA -> sincos -> 3 L1 MFMAs -> 3x(ELU+MFMA) -> ELU+head MFMA -> store.
// launch_bounds(128,5): cap VGPR at 102 -> 5 waves/SIMD (was 4) for +25%
// latency-hiding on the serial per-sub-batch dependency chain.
__global__ __launch_bounds__(128, 5) void pixenc_mfma10(
    const float* __restrict__ x,
    const float* __restrict__ Bl,
    const float* __restrict__ W1, const float* __restrict__ b1,
    const float* __restrict__ W2, const float* __restrict__ b2,
    const float* __restrict__ W3, const float* __restrict__ b3,
    const float* __restrict__ W4, const float* __restrict__ b4,
    const float* __restrict__ W5, const float* __restrict__ b5,
    float* __restrict__ out)
{
    const int t    = threadIdx.x;
    const int lane = t & 63;
    const int w    = t >> 6;
    const int g    = lane >> 4;
    const int m    = lane & 15;

    // ---- per-lane weight fragments; A1/c1..c4 pre-scaled by log2e ----
    half4_t A1[3], A2, A3, A4;
    #pragma unroll
    for (int e = 0; e < 4; ++e) {
        const int c0 = 4 * e + g;                 // layer-1 slot (g,e) -> x col
        A1[0][e] = (c0 < 9) ? (_Float16)(W1[c0 * 16 + m] * LOG2E) : (_Float16)0.f;
        A1[1][e] = (_Float16)(W1[(9  + g * 4 + e) * 16 + m] * LOG2E);
        A1[2][e] = (_Float16)(W1[(25 + g * 4 + e) * 16 + m] * LOG2E);
        A2[e]    = (_Float16)W2[(g * 4 + e) * 16 + m];
        A3[e]    = (_Float16)W3[(g * 4 + e) * 16 + m];
        A4[e]    = (_Float16)W4[(g * 4 + e) * 16 + m];
    }
    // z-MFMA A: row f: k0 -> Bl_row0[f], k1 -> Bl_row1[f]; zero cols k>=2.
    const half4_t Az = (g == 0) ? mkfrag(pk(Bl[m], Bl[16 + m]), 0u)
                                : mkfrag(0u, 0u);
    // head A: row 0 = W5 * ln2 (un-scales H4' = log2e*H4)
    const half4_t A5 = (m == 0)
        ? mkfrag(pk(W5[g * 4 + 0] * LN2, W5[g * 4 + 1] * LN2),
                 pk(W5[g * 4 + 2] * LN2, W5[g * 4 + 3] * LN2))
        : mkfrag(0u, 0u);
    f32x4 c1, c2, c3, c4;
    #pragma unroll
    for (int e = 0; e < 4; ++e) {
        const int r = g * 4 + e;
        c1[e] = b1[r] * LOG2E; c2[e] = b2[r] * LOG2E;
        c3[e] = b3[r] * LOG2E; c4[e] = b4[r] * LOG2E;
    }
    const f32x4 zero4 = {0.f, 0.f, 0.f, 0.f};
    f32x4 c5 = zero4;
    if (g == 0) c5[0] = b5[0];                    // b5 via head C-in row 0

    const int wavebase = blockIdx.x * (128 * CH) + w * (64 * CH);

    // per-lane base pointers; all loop loads use compile-time offsets
    const float* aA = x + (size_t)(wavebase + m) * 11 + g;   // cols g, 4+g
    const float* aB = x + (size_t)(wavebase + m) * 11 + 8;   // cols 8,9,10
    float* outp = out + wavebase + m;

    // ---- prologue: load+pack chunk 0 ----
    unsigned cp0[4], cp8[4], cbz[4];
    #pragma unroll
    for (int s = 0; s < 4; ++s) {
        const float a0 = aA[s * 176], a1 = aA[s * 176 + 4];
        const float b8 = aB[s * 176], b9 = aB[s * 176 + 1], b10 = aB[s * 176 + 2];
        cp0[s] = pk(a0, a1); cp8[s] = pk(b8, 0.f);
        cbz[s] = pk(b9, b10);          // garbage B-rows k>=4 hit zero A cols
    }

    #pragma unroll
    for (int c = 0; c < CH; ++c) {
        // ---- prefetch chunk c+1 (advance pointers, immediate offsets) ----
        unsigned np0[4], np8[4], nbz[4];
        if (c + 1 < CH) {
            aA += 704; aB += 704;                 // 64 samples * 11 floats
            #pragma unroll
            for (int s = 0; s < 4; ++s) {
                const float a0 = aA[s * 176], a1 = aA[s * 176 + 4];
                const float b8 = aB[s * 176], b9 = aB[s * 176 + 1], b10 = aB[s * 176 + 2];
                np0[s] = pk(a0, a1); np8[s] = pk(b8, 0.f);
                nbz[s] = pk(b9, b10);
            }
        }

        // ---- z-MFMAs for all 4 sub-batches (independent, pipelined) ----
        f32x4 az[4];
        #pragma unroll
        for (int s = 0; s < 4; ++s)
            az[s] = __builtin_amdgcn_mfma_f32_16x16x16f16(
                        Az, mkfrag(cbz[s], 0u), zero4, 0, 0, 0);

        // ---- layer 1: trans + fragment build + 3-MFMA chain per s ----
        f32x4 acc[4];
        #pragma unroll
        for (int s = 0; s < 4; ++s) {
            float cs[4], sn[4];
            #pragma unroll
            for (int e = 0; e < 4; ++e) {
                const float zf = __builtin_amdgcn_fractf(az[s][e]);
                cs[e] = __builtin_amdgcn_cosf(zf);
                sn[e] = __builtin_amdgcn_sinf(zf);
            }
            const half4_t F0 = mkfrag(cp0[s], cp8[s]);
            const half4_t F1 = mkfrag(pk(cs[0], cs[1]), pk(cs[2], cs[3]));
            const half4_t F2 = mkfrag(pk(sn[0], sn[1]), pk(sn[2], sn[3]));
            f32x4 a = c1;
            a = __builtin_amdgcn_mfma_f32_16x16x16f16(A1[0], F0, a, 0, 0, 0);
            a = __builtin_amdgcn_mfma_f32_16x16x16f16(A1[1], F1, a, 0, 0, 0);
            a = __builtin_amdgcn_mfma_f32_16x16x16f16(A1[2], F2, a, 0, 0, 0);
            acc[s] = a;
        }

        // ---- layers 2-4: 4 independent chains, interleaved ----
        half4_t H[4];
        #pragma unroll
        for (int s = 0; s < 4; ++s)
            H[s] = mkfrag(elu_pk(acc[s][0], acc[s][1]), elu_pk(acc[s][2], acc[s][3]));
        #pragma unroll
        for (int s = 0; s < 4; ++s)
            acc[s] = __builtin_amdgcn_mfma_f32_16x16x16f16(A2, H[s], c2, 0, 0, 0);

        #pragma unroll
        for (int s = 0; s < 4; ++s)
            H[s] = mkfrag(elu_pk(acc[s][0], acc[s][1]), elu_pk(acc[s][2], acc[s][3]));
        #pragma unroll
        for (int s = 0; s < 4; ++s)
            acc[s] = __builtin_amdgcn_mfma_f32_16x16x16f16(A3, H[s], c3, 0, 0, 0);

        #pragma unroll
        for (int s = 0; s < 4; ++s)
            H[s] = mkfrag(elu_pk(acc[s][0], acc[s][1]), elu_pk(acc[s][2], acc[s][3]));
        #pragma unroll
        for (int s = 0; s < 4; ++s)
            acc[s] = __builtin_amdgcn_mfma_f32_16x16x16f16(A4, H[s], c4, 0, 0, 0);

        // ---- head: ELU + head-MFMA (b5 in C); row 0 = outputs; store ----
        #pragma unroll
        for (int s = 0; s < 4; ++s)
            H[s] = mkfrag(elu_pk(acc[s][0], acc[s][1]), elu_pk(acc[s][2], acc[s][3]));
        #pragma unroll
        for (int s = 0; s < 4; ++s) {
            const f32x4 oh = __builtin_amdgcn_mfma_f32_16x16x16f16(
                                 A5, H[s], c5, 0, 0, 0);
            if (g == 0) outp[c * 64 + s * 16] = oh[0];
        }

        // ---- rotate prefetch ----
        if (c + 1 < CH) {
            #pragma unroll
            for (int s = 0; s < 4; ++s) {
                cp0[s] = np0[s]; cp8[s] = np8[s]; cbz[s] = nbz[s];
            }
        }
    }
}

// Guarded scalar tail (only launched when N % 1024 != 0; never for N=8388608).
__global__ void pixenc_tail(
    const float* __restrict__ x, const float* __restrict__ Bl,
    const float* __restrict__ W1, const float* __restrict__ b1,
    const float* __restrict__ W2, const float* __restrict__ b2,
    const float* __restrict__ W3, const float* __restrict__ b3,
    const float* __restrict__ W4, const float* __restrict__ b4,
    const float* __restrict__ W5, const float* __restrict__ b5,
    float* __restrict__ out, int N, int start)
{
    const int i = start + blockIdx.x * 256 + threadIdx.x;
    if (i >= N) return;
    const float* xr = x + (size_t)i * 11;
    float feats[41];
    for (int k = 0; k < 9; ++k) feats[k] = xr[k];
    for (int f = 0; f < 16; ++f) {
        const float ang = 6.283185f * (xr[9] * Bl[f] + xr[10] * Bl[16 + f]);
        float s, c; __sincosf(ang, &s, &c);
        feats[9 + f] = c; feats[25 + f] = s;
    }
    float h[16], gg[16];
    for (int j = 0; j < 16; ++j) h[j] = b1[j];
    for (int k = 0; k < 41; ++k)
        for (int j = 0; j < 16; ++j) h[j] = fmaf(feats[k], W1[k * 16 + j], h[j]);
    for (int j = 0; j < 16; ++j) h[j] = h[j] > 0.f ? h[j] : __expf(h[j]) - 1.f;
    for (int j = 0; j < 16; ++j) gg[j] = b2[j];
    for (int k = 0; k < 16; ++k)
        for (int j = 0; j < 16; ++j) gg[j] = fmaf(h[k], W2[k * 16 + j], gg[j]);
    for (int j = 0; j < 16; ++j) gg[j] = gg[j] > 0.f ? gg[j] : __expf(gg[j]) - 1.f;
    for (int j = 0; j < 16; ++j) h[j] = b3[j];
    for (int k = 0; k < 16; ++k)
        for (int j = 0; j < 16; ++j) h[j] = fmaf(gg[k], W3[k * 16 + j], h[j]);
    for (int j = 0; j < 16; ++j) h[j] = h[j] > 0.f ? h[j] : __expf(h[j]) - 1.f;
    for (int j = 0; j < 16; ++j) gg[j] = b4[j];
    for (int k = 0; k < 16; ++k)
        for (int j = 0; j < 16; ++j) gg[j] = fmaf(h[k], W4[k * 16 + j], gg[j]);
    for (int j = 0; j < 16; ++j) gg[j] = gg[j] > 0.f ? gg[j] : __expf(gg[j]) - 1.f;
    float o = b5[0];
    for (int j = 0; j < 16; ++j) o = fmaf(gg[j], W5[j], o);
    out[i] = o;
}

extern "C" void kernel_launch(void* const* d_in, const int* in_sizes, int n_in,
                              void* d_out, int out_size, void* d_ws, size_t ws_size,
                              hipStream_t stream) {
    const float* x  = (const float*)d_in[0];
    const float* Bl = (const float*)d_in[1];
    const float* W1 = (const float*)d_in[2];
    const float* b1 = (const float*)d_in[3];
    const float* W2 = (const float*)d_in[4];
    const float* b2 = (const float*)d_in[5];
    const float* W3 = (const float*)d_in[6];
    const float* b3 = (const float*)d_in[7];
    const float* W4 = (const float*)d_in[8];
    const float* b4 = (const float*)d_in[9];
    const float* W5 = (const float*)d_in[10];
    const float* b5 = (const float*)d_in[11];
    float* out = (float*)d_out;

    const int N = out_size;
    const int NB = N / (128 * CH);
    const int rem = N - NB * (128 * CH);
    if (NB > 0)
        pixenc_mfma10<<<NB, 128, 0, stream>>>(x, Bl, W1, b1, W2, b2, W3, b3,
                                              W4, b4, W5, b5, out);
    if (rem > 0)
        pixenc_tail<<<(rem + 255) / 256, 256, 0, stream>>>(
            x, Bl, W1, b1, W2, b2, W3, b3, W4, b4, W5, b5, out, N, NB * 128 * CH);
}

// Round 13
// 122.305 us; speedup vs baseline: 1.2080x; 1.0370x over previous
//
#include <hip/hip_runtime.h>

typedef __fp16   cvt16x2 __attribute__((ext_vector_type(2)));
typedef _Float16 h2      __attribute__((ext_vector_type(2)));
typedef _Float16 half4_t __attribute__((ext_vector_type(4)));
typedef unsigned uint2v  __attribute__((ext_vector_type(2)));
typedef float    f32x4   __attribute__((ext_vector_type(4)));
// 4-byte-aligned float pair: backend emits global_load_dwordx2 (gfx950 has
// unaligned-access-mode, so 4B-aligned x2 loads are legal).
typedef float    f32x2u  __attribute__((ext_vector_type(2), aligned(4)));

#define CH 8   // 64-sample chunks per wave; 128-thread block => 1024 samples
#define LOG2E 1.44269504f
#define LN2   0.69314718f

#if !__has_builtin(__builtin_elementwise_exp2)
extern "C" __device__ _Float16 __ocml_exp2_f16(_Float16);
#endif

__device__ __forceinline__ unsigned pk(float a, float b) {
    cvt16x2 h = __builtin_amdgcn_cvt_pkrtz(a, b);
    return __builtin_bit_cast(unsigned, h);
}
__device__ __forceinline__ half4_t mkfrag(unsigned lo, unsigned hi) {
    uint2v u; u[0] = lo; u[1] = hi;
    return __builtin_bit_cast(half4_t, u);
}

// Scaled-domain ELU (hardware v_exp_f16).
// Input v' = v*log2e; output H' = max(v', exp2(min(v',0))*lg - lg).
__device__ __forceinline__ unsigned elu_pk(float a, float b) {
    h2 v = __builtin_bit_cast(h2, __builtin_amdgcn_cvt_pkrtz(a, b));
    const h2 z   = {(_Float16)0.f, (_Float16)0.f};
    const h2 lg  = {(_Float16)LOG2E, (_Float16)LOG2E};
    const h2 mlg = {(_Float16)(-LOG2E), (_Float16)(-LOG2E)};
    h2 t = __builtin_elementwise_min(v, z);
#if __has_builtin(__builtin_elementwise_exp2)
    h2 ev = __builtin_elementwise_exp2(t);
#else
    h2 ev; ev[0] = __ocml_exp2_f16(t[0]); ev[1] = __ocml_exp2_f16(t[1]);
#endif
    h2 r = __builtin_elementwise_max(v, ev * lg + mlg);   // v_pk_fma_f16
    return __builtin_bit_cast(unsigned, r);
}

// No LDS, no barriers, no shuffles. 3 VMEM per sub-batch (dwordx2 + dword +
// dwordx2) via layer-1 slot permutation: lane (g,m) c0-slots are cols
// {2g, 2g+1, 8 (g==0 only)}; dead slots have zero A1 rows.
__global__ __launch_bounds__(128, 4) void pixenc_mfma11(
    const float* __restrict__ x,
    const float* __restrict__ Bl,
    const float* __restrict__ W1, const float* __restrict__ b1,
    const float* __restrict__ W2, const float* __restrict__ b2,
    const float* __restrict__ W3, const float* __restrict__ b3,
    const float* __restrict__ W4, const float* __restrict__ b4,
    const float* __restrict__ W5, const float* __restrict__ b5,
    float* __restrict__ out)
{
    const int t    = threadIdx.x;
    const int lane = t & 63;
    const int w    = t >> 6;
    const int g    = lane >> 4;
    const int m    = lane & 15;

    // ---- per-lane weight fragments; A1/c1..c4 pre-scaled by log2e ----
    half4_t A1[3], A2, A3, A4;
    {
        // c0-slot (g,e) -> W1 feature row: e0->2g, e1->2g+1, e2->8 iff g==0
        A1[0][0] = (_Float16)(W1[(2 * g) * 16 + m] * LOG2E);
        A1[0][1] = (_Float16)(W1[(2 * g + 1) * 16 + m] * LOG2E);
        A1[0][2] = (g == 0) ? (_Float16)(W1[8 * 16 + m] * LOG2E) : (_Float16)0.f;
        A1[0][3] = (_Float16)0.f;
    }
    #pragma unroll
    for (int e = 0; e < 4; ++e) {
        A1[1][e] = (_Float16)(W1[(9  + g * 4 + e) * 16 + m] * LOG2E);
        A1[2][e] = (_Float16)(W1[(25 + g * 4 + e) * 16 + m] * LOG2E);
        A2[e]    = (_Float16)W2[(g * 4 + e) * 16 + m];
        A3[e]    = (_Float16)W3[(g * 4 + e) * 16 + m];
        A4[e]    = (_Float16)W4[(g * 4 + e) * 16 + m];
    }
    // z-MFMA A: row f: k0 -> Bl_row0[f], k1 -> Bl_row1[f]; zero cols k>=2.
    const half4_t Az = (g == 0) ? mkfrag(pk(Bl[m], Bl[16 + m]), 0u)
                                : mkfrag(0u, 0u);
    // head A: row 0 = W5 * ln2 (un-scales H4' = log2e*H4)
    const half4_t A5 = (m == 0)
        ? mkfrag(pk(W5[g * 4 + 0] * LN2, W5[g * 4 + 1] * LN2),
                 pk(W5[g * 4 + 2] * LN2, W5[g * 4 + 3] * LN2))
        : mkfrag(0u, 0u);
    f32x4 c1, c2, c3, c4;
    #pragma unroll
    for (int e = 0; e < 4; ++e) {
        const int r = g * 4 + e;
        c1[e] = b1[r] * LOG2E; c2[e] = b2[r] * LOG2E;
        c3[e] = b3[r] * LOG2E; c4[e] = b4[r] * LOG2E;
    }
    const f32x4 zero4 = {0.f, 0.f, 0.f, 0.f};
    f32x4 c5 = zero4;
    if (g == 0) c5[0] = b5[0];                    // b5 via head C-in row 0

    const int wavebase = blockIdx.x * (128 * CH) + w * (64 * CH);

    // per-lane base pointers; all loop loads use compile-time offsets
    const float* aA = x + (size_t)(wavebase + m) * 11 + 2 * g; // cols 2g,2g+1
    const float* aB = x + (size_t)(wavebase + m) * 11 + 8;     // cols 8 | 9,10
    float* outp = out + wavebase + m;

    // ---- prologue: load+pack chunk 0 ----
    unsigned cp0[4], cp8[4], cbz[4];
    #pragma unroll
    for (int s = 0; s < 4; ++s) {
        const f32x2u va = *(const f32x2u*)(aA + s * 176);      // dwordx2
        const float  b8 = aB[s * 176];                          // dword
        const f32x2u vz = *(const f32x2u*)(aB + s * 176 + 1);  // dwordx2 (9,10)
        cp0[s] = pk(va[0], va[1]); cp8[s] = pk(b8, 0.f);
        cbz[s] = pk(vz[0], vz[1]);
    }

    #pragma unroll
    for (int c = 0; c < CH; ++c) {
        // ---- prefetch chunk c+1 (advance pointers, immediate offsets) ----
        unsigned np0[4], np8[4], nbz[4];
        if (c + 1 < CH) {
            aA += 704; aB += 704;                 // 64 samples * 11 floats
            #pragma unroll
            for (int s = 0; s < 4; ++s) {
                const f32x2u va = *(const f32x2u*)(aA + s * 176);
                const float  b8 = aB[s * 176];
                const f32x2u vz = *(const f32x2u*)(aB + s * 176 + 1);
                np0[s] = pk(va[0], va[1]); np8[s] = pk(b8, 0.f);
                nbz[s] = pk(vz[0], vz[1]);
            }
        }

        // ---- z-MFMAs for all 4 sub-batches (independent, pipelined) ----
        f32x4 az[4];
        #pragma unroll
        for (int s = 0; s < 4; ++s)
            az[s] = __builtin_amdgcn_mfma_f32_16x16x16f16(
                        Az, mkfrag(cbz[s], 0u), zero4, 0, 0, 0);

        // ---- layer 1: trans + fragment build + 3-MFMA chain per s ----
        f32x4 acc[4];
        #pragma unroll
        for (int s = 0; s < 4; ++s) {
            float cs[4], sn[4];
            #pragma unroll
            for (int e = 0; e < 4; ++e) {
                const float zf = __builtin_amdgcn_fractf(az[s][e]);
                cs[e] = __builtin_amdgcn_cosf(zf);
                sn[e] = __builtin_amdgcn_sinf(zf);
            }
            const half4_t F0 = mkfrag(cp0[s], cp8[s]);
            const half4_t F1 = mkfrag(pk(cs[0], cs[1]), pk(cs[2], cs[3]));
            const half4_t F2 = mkfrag(pk(sn[0], sn[1]), pk(sn[2], sn[3]));
            f32x4 a = c1;
            a = __builtin_amdgcn_mfma_f32_16x16x16f16(A1[0], F0, a, 0, 0, 0);
            a = __builtin_amdgcn_mfma_f32_16x16x16f16(A1[1], F1, a, 0, 0, 0);
            a = __builtin_amdgcn_mfma_f32_16x16x16f16(A1[2], F2, a, 0, 0, 0);
            acc[s] = a;
        }

        // ---- layers 2-4: 4 independent chains, interleaved ----
        half4_t H[4];
        #pragma unroll
        for (int s = 0; s < 4; ++s)
            H[s] = mkfrag(elu_pk(acc[s][0], acc[s][1]), elu_pk(acc[s][2], acc[s][3]));
        #pragma unroll
        for (int s = 0; s < 4; ++s)
            acc[s] = __builtin_amdgcn_mfma_f32_16x16x16f16(A2, H[s], c2, 0, 0, 0);

        #pragma unroll
        for (int s = 0; s < 4; ++s)
            H[s] = mkfrag(elu_pk(acc[s][0], acc[s][1]), elu_pk(acc[s][2], acc[s][3]));
        #pragma unroll
        for (int s = 0; s < 4; ++s)
            acc[s] = __builtin_amdgcn_mfma_f32_16x16x16f16(A3, H[s], c3, 0, 0, 0);

        #pragma unroll
        for (int s = 0; s < 4; ++s)
            H[s] = mkfrag(elu_pk(acc[s][0], acc[s][1]), elu_pk(acc[s][2], acc[s][3]));
        #pragma unroll
        for (int s = 0; s < 4; ++s)
            acc[s] = __builtin_amdgcn_mfma_f32_16x16x16f16(A4, H[s], c4, 0, 0, 0);

        // ---- head: ELU + head-MFMA (b5 in C); row 0 = outputs; store ----
        #pragma unroll
        for (int s = 0; s < 4; ++s)
            H[s] = mkfrag(elu_pk(acc[s][0], acc[s][1]), elu_pk(acc[s][2], acc[s][3]));
        #pragma unroll
        for (int s = 0; s < 4; ++s) {
            const f32x4 oh = __builtin_amdgcn_mfma_f32_16x16x16f16(
                                 A5, H[s], c5, 0, 0, 0);
            if (g == 0) outp[c * 64 + s * 16] = oh[0];
        }

        // ---- rotate prefetch ----
        if (c + 1 < CH) {
            #pragma unroll
            for (int s = 0; s < 4; ++s) {
                cp0[s] = np0[s]; cp8[s] = np8[s]; cbz[s] = nbz[s];
            }
        }
    }
}

// Guarded scalar tail (only launched when N % 1024 != 0; never for N=8388608).
__global__ void pixenc_tail(
    const float* __restrict__ x, const float* __restrict__ Bl,
    const float* __restrict__ W1, const float* __restrict__ b1,
    const float* __restrict__ W2, const float* __restrict__ b2,
    const float* __restrict__ W3, const float* __restrict__ b3,
    const float* __restrict__ W4, const float* __restrict__ b4,
    const float* __restrict__ W5, const float* __restrict__ b5,
    float* __restrict__ out, int N, int start)
{
    const int i = start + blockIdx.x * 256 + threadIdx.x;
    if (i >= N) return;
    const float* xr = x + (size_t)i * 11;
    float feats[41];
    for (int k = 0; k < 9; ++k) feats[k] = xr[k];
    for (int f = 0; f < 16; ++f) {
        const float ang = 6.283185f * (xr[9] * Bl[f] + xr[10] * Bl[16 + f]);
        float s, c; __sincosf(ang, &s, &c);
        feats[9 + f] = c; feats[25 + f] = s;
    }
    float h[16], gg[16];
    for (int j = 0; j < 16; ++j) h[j] = b1[j];
    for (int k = 0; k < 41; ++k)
        for (int j = 0; j < 16; ++j) h[j] = fmaf(feats[k], W1[k * 16 + j], h[j]);
    for (int j = 0; j < 16; ++j) h[j] = h[j] > 0.f ? h[j] : __expf(h[j]) - 1.f;
    for (int j = 0; j < 16; ++j) gg[j] = b2[j];
    for (int k = 0; k < 16; ++k)
        for (int j = 0; j < 16; ++j) gg[j] = fmaf(h[k], W2[k * 16 + j], gg[j]);
    for (int j = 0; j < 16; ++j) gg[j] = gg[j] > 0.f ? gg[j] : __expf(gg[j]) - 1.f;
    for (int j = 0; j < 16; ++j) h[j] = b3[j];
    for (int k = 0; k < 16; ++k)
        for (int j = 0; j < 16; ++j) h[j] = fmaf(gg[k], W3[k * 16 + j], h[j]);
    for (int j = 0; j < 16; ++j) h[j] = h[j] > 0.f ? h[j] : __expf(h[j]) - 1.f;
    for (int j = 0; j < 16; ++j) gg[j] = b4[j];
    for (int k = 0; k < 16; ++k)
        for (int j = 0; j < 16; ++j) gg[j] = fmaf(h[k], W4[k * 16 + j], gg[j]);
    for (int j = 0; j < 16; ++j) gg[j] = gg[j] > 0.f ? gg[j] : __expf(gg[j]) - 1.f;
    float o = b5[0];
    for (int j = 0; j < 16; ++j) o = fmaf(gg[j], W5[j], o);
    out[i] = o;
}

extern "C" void kernel_launch(void* const* d_in, const int* in_sizes, int n_in,
                              void* d_out, int out_size, void* d_ws, size_t ws_size,
                              hipStream_t stream) {
    const float* x  = (const float*)d_in[0];
    const float* Bl = (const float*)d_in[1];
    const float* W1 = (const float*)d_in[2];
    const float* b1 = (const float*)d_in[3];
    const float* W2 = (const float*)d_in[4];
    const float* b2 = (const float*)d_in[5];
    const float* W3 = (const float*)d_in[6];
    const float* b3 = (const float*)d_in[7];
    const float* W4 = (const float*)d_in[8];
    const float* b4 = (const float*)d_in[9];
    const float* W5 = (const float*)d_in[10];
    const float* b5 = (const float*)d_in[11];
    float* out = (float*)d_out;

    const int N = out_size;
    const int NB = N / (128 * CH);
    const int rem = N - NB * (128 * CH);
    if (NB > 0)
        pixenc_mfma11<<<NB, 128, 0, stream>>>(x, Bl, W1, b1, W2, b2, W3, b3,
                                              W4, b4, W5, b5, out);
    if (rem > 0)
        pixenc_tail<<<(rem + 255) / 256, 256, 0, stream>>>(
            x, Bl, W1, b1, W2, b2, W3, b3, W4, b4, W5, b5, out, N, NB * 128 * CH);
}

// Round 14
// 121.267 us; speedup vs baseline: 1.2183x; 1.0086x over previous
//
#include <hip/hip_runtime.h>

typedef __fp16   cvt16x2 __attribute__((ext_vector_type(2)));
typedef _Float16 h2      __attribute__((ext_vector_type(2)));
typedef _Float16 half4_t __attribute__((ext_vector_type(4)));
typedef unsigned uint2v  __attribute__((ext_vector_type(2)));
typedef float    f32x4   __attribute__((ext_vector_type(4)));
// 4-byte-aligned float quad: gfx950 unaligned-access-mode lets the backend
// emit global_load_dwordx4 at 4B alignment.
typedef float    f32x4u  __attribute__((ext_vector_type(4), aligned(4)));

#define CH 8   // 64-sample chunks per wave; 128-thread block => 1024 samples
#define LOG2E 1.44269504f
#define LN2   0.69314718f

#if !__has_builtin(__builtin_elementwise_exp2)
extern "C" __device__ _Float16 __ocml_exp2_f16(_Float16);
#endif

__device__ __forceinline__ unsigned pk(float a, float b) {
    cvt16x2 h = __builtin_amdgcn_cvt_pkrtz(a, b);
    return __builtin_bit_cast(unsigned, h);
}
__device__ __forceinline__ half4_t mkfrag(unsigned lo, unsigned hi) {
    uint2v u; u[0] = lo; u[1] = hi;
    return __builtin_bit_cast(half4_t, u);
}

// Scaled-domain ELU (hardware v_exp_f16).
// Input v' = v*log2e; output H' = max(v', exp2(min(v',0))*lg - lg).
__device__ __forceinline__ unsigned elu_pk(float a, float b) {
    h2 v = __builtin_bit_cast(h2, __builtin_amdgcn_cvt_pkrtz(a, b));
    const h2 z   = {(_Float16)0.f, (_Float16)0.f};
    const h2 lg  = {(_Float16)LOG2E, (_Float16)LOG2E};
    const h2 mlg = {(_Float16)(-LOG2E), (_Float16)(-LOG2E)};
    h2 t = __builtin_elementwise_min(v, z);
#if __has_builtin(__builtin_elementwise_exp2)
    h2 ev = __builtin_elementwise_exp2(t);
#else
    h2 ev; ev[0] = __ocml_exp2_f16(t[0]); ev[1] = __ocml_exp2_f16(t[1]);
#endif
    h2 r = __builtin_elementwise_max(v, ev * lg + mlg);   // v_pk_fma_f16
    return __builtin_bit_cast(unsigned, r);
}

// ONE dwordx4 per lane per sub-batch. Per-g 16B column windows:
//   g=0: cols 7..10  (feats 7,8; cols 9,10 = z-B-fragment, dead in F0)
//   g=1: cols 0..3   g=2: cols 3..6 (col3 dup dead)   g=3: dead (A1 rows 0)
// The packed upper half of g=0's window (cols 9,10) IS cbz for the z-MFMA
// (k=0,1 live in g=0 lanes); other lanes' cbz is garbage killed by zero
// A-columns. No LDS, no barriers, no shuffles.
__global__ __launch_bounds__(128, 4) void pixenc_mfma12(
    const float* __restrict__ x,
    const float* __restrict__ Bl,
    const float* __restrict__ W1, const float* __restrict__ b1,
    const float* __restrict__ W2, const float* __restrict__ b2,
    const float* __restrict__ W3, const float* __restrict__ b3,
    const float* __restrict__ W4, const float* __restrict__ b4,
    const float* __restrict__ W5, const float* __restrict__ b5,
    float* __restrict__ out)
{
    const int t    = threadIdx.x;
    const int lane = t & 63;
    const int w    = t >> 6;
    const int g    = lane >> 4;
    const int m    = lane & 15;

    // per-g window start column: {7,0,3,0}
    const int coff = (g == 0) ? 7 : (g == 2) ? 3 : 0;

    // ---- per-lane weight fragments; A1/c1..c4 pre-scaled by log2e ----
    half4_t A1[3], A2, A3, A4;
    #pragma unroll
    for (int e = 0; e < 4; ++e) {
        // slot (g,e) covers feature col coff+e; valid iff non-dup real col
        const bool valid = (g == 1) | (g == 0 && e < 2) | (g == 2 && e >= 1);
        A1[0][e] = valid ? (_Float16)(W1[(coff + e) * 16 + m] * LOG2E)
                         : (_Float16)0.f;
        A1[1][e] = (_Float16)(W1[(9  + g * 4 + e) * 16 + m] * LOG2E);
        A1[2][e] = (_Float16)(W1[(25 + g * 4 + e) * 16 + m] * LOG2E);
        A2[e]    = (_Float16)W2[(g * 4 + e) * 16 + m];
        A3[e]    = (_Float16)W3[(g * 4 + e) * 16 + m];
        A4[e]    = (_Float16)W4[(g * 4 + e) * 16 + m];
    }
    // z-MFMA A: row f: k0 -> Bl_row0[f], k1 -> Bl_row1[f]; zero cols k>=2.
    const half4_t Az = (g == 0) ? mkfrag(pk(Bl[m], Bl[16 + m]), 0u)
                                : mkfrag(0u, 0u);
    // head A: row 0 = W5 * ln2 (un-scales H4' = log2e*H4)
    const half4_t A5 = (m == 0)
        ? mkfrag(pk(W5[g * 4 + 0] * LN2, W5[g * 4 + 1] * LN2),
                 pk(W5[g * 4 + 2] * LN2, W5[g * 4 + 3] * LN2))
        : mkfrag(0u, 0u);
    f32x4 c1, c2, c3, c4;
    #pragma unroll
    for (int e = 0; e < 4; ++e) {
        const int r = g * 4 + e;
        c1[e] = b1[r] * LOG2E; c2[e] = b2[r] * LOG2E;
        c3[e] = b3[r] * LOG2E; c4[e] = b4[r] * LOG2E;
    }
    const f32x4 zero4 = {0.f, 0.f, 0.f, 0.f};
    f32x4 c5 = zero4;
    if (g == 0) c5[0] = b5[0];                    // b5 via head C-in row 0

    const int wavebase = blockIdx.x * (128 * CH) + w * (64 * CH);

    // single per-lane base pointer; all loop loads use compile-time offsets
    const float* aP = x + (size_t)(wavebase + m) * 11 + coff;
    float* outp = out + wavebase + m;

    // ---- prologue: load+pack chunk 0 ----
    unsigned cp01[4], cp23[4];
    #pragma unroll
    for (int s = 0; s < 4; ++s) {
        const f32x4u v = *(const f32x4u*)(aP + s * 176);   // one dwordx4
        cp01[s] = pk(v[0], v[1]);
        cp23[s] = pk(v[2], v[3]);   // g=0: (cols 9,10) = z fragment
    }

    #pragma unroll
    for (int c = 0; c < CH; ++c) {
        // ---- prefetch chunk c+1 (advance pointer, immediate offsets) ----
        unsigned np01[4], np23[4];
        if (c + 1 < CH) {
            aP += 704;                            // 64 samples * 11 floats
            #pragma unroll
            for (int s = 0; s < 4; ++s) {
                const f32x4u v = *(const f32x4u*)(aP + s * 176);
                np01[s] = pk(v[0], v[1]);
                np23[s] = pk(v[2], v[3]);
            }
        }

        // ---- z-MFMAs for all 4 sub-batches (independent, pipelined) ----
        f32x4 az[4];
        #pragma unroll
        for (int s = 0; s < 4; ++s)
            az[s] = __builtin_amdgcn_mfma_f32_16x16x16f16(
                        Az, mkfrag(cp23[s], 0u), zero4, 0, 0, 0);

        // ---- layer 1: trans + fragment build + 3-MFMA chain per s ----
        f32x4 acc[4];
        #pragma unroll
        for (int s = 0; s < 4; ++s) {
            float cs[4], sn[4];
            #pragma unroll
            for (int e = 0; e < 4; ++e) {
                const float zf = __builtin_amdgcn_fractf(az[s][e]);
                cs[e] = __builtin_amdgcn_cosf(zf);
                sn[e] = __builtin_amdgcn_sinf(zf);
            }
            const half4_t F0 = mkfrag(cp01[s], cp23[s]);  // upper dead if g==0
            const half4_t F1 = mkfrag(pk(cs[0], cs[1]), pk(cs[2], cs[3]));
            const half4_t F2 = mkfrag(pk(sn[0], sn[1]), pk(sn[2], sn[3]));
            f32x4 a = c1;
            a = __builtin_amdgcn_mfma_f32_16x16x16f16(A1[0], F0, a, 0, 0, 0);
            a = __builtin_amdgcn_mfma_f32_16x16x16f16(A1[1], F1, a, 0, 0, 0);
            a = __builtin_amdgcn_mfma_f32_16x16x16f16(A1[2], F2, a, 0, 0, 0);
            acc[s] = a;
        }

        // ---- layers 2-4: 4 independent chains, interleaved ----
        half4_t H[4];
        #pragma unroll
        for (int s = 0; s < 4; ++s)
            H[s] = mkfrag(elu_pk(acc[s][0], acc[s][1]), elu_pk(acc[s][2], acc[s][3]));
        #pragma unroll
        for (int s = 0; s < 4; ++s)
            acc[s] = __builtin_amdgcn_mfma_f32_16x16x16f16(A2, H[s], c2, 0, 0, 0);

        #pragma unroll
        for (int s = 0; s < 4; ++s)
            H[s] = mkfrag(elu_pk(acc[s][0], acc[s][1]), elu_pk(acc[s][2], acc[s][3]));
        #pragma unroll
        for (int s = 0; s < 4; ++s)
            acc[s] = __builtin_amdgcn_mfma_f32_16x16x16f16(A3, H[s], c3, 0, 0, 0);

        #pragma unroll
        for (int s = 0; s < 4; ++s)
            H[s] = mkfrag(elu_pk(acc[s][0], acc[s][1]), elu_pk(acc[s][2], acc[s][3]));
        #pragma unroll
        for (int s = 0; s < 4; ++s)
            acc[s] = __builtin_amdgcn_mfma_f32_16x16x16f16(A4, H[s], c4, 0, 0, 0);

        // ---- head: ELU + head-MFMA (b5 in C); row 0 = outputs; store ----
        #pragma unroll
        for (int s = 0; s < 4; ++s)
            H[s] = mkfrag(elu_pk(acc[s][0], acc[s][1]), elu_pk(acc[s][2], acc[s][3]));
        #pragma unroll
        for (int s = 0; s < 4; ++s) {
            const f32x4 oh = __builtin_amdgcn_mfma_f32_16x16x16f16(
                                 A5, H[s], c5, 0, 0, 0);
            if (g == 0) outp[c * 64 + s * 16] = oh[0];
        }

        // ---- rotate prefetch ----
        if (c + 1 < CH) {
            #pragma unroll
            for (int s = 0; s < 4; ++s) {
                cp01[s] = np01[s]; cp23[s] = np23[s];
            }
        }
    }
}

// Guarded scalar tail (only launched when N % 1024 != 0; never for N=8388608).
__global__ void pixenc_tail(
    const float* __restrict__ x, const float* __restrict__ Bl,
    const float* __restrict__ W1, const float* __restrict__ b1,
    const float* __restrict__ W2, const float* __restrict__ b2,
    const float* __restrict__ W3, const float* __restrict__ b3,
    const float* __restrict__ W4, const float* __restrict__ b4,
    const float* __restrict__ W5, const float* __restrict__ b5,
    float* __restrict__ out, int N, int start)
{
    const int i = start + blockIdx.x * 256 + threadIdx.x;
    if (i >= N) return;
    const float* xr = x + (size_t)i * 11;
    float feats[41];
    for (int k = 0; k < 9; ++k) feats[k] = xr[k];
    for (int f = 0; f < 16; ++f) {
        const float ang = 6.283185f * (xr[9] * Bl[f] + xr[10] * Bl[16 + f]);
        float s, c; __sincosf(ang, &s, &c);
        feats[9 + f] = c; feats[25 + f] = s;
    }
    float h[16], gg[16];
    for (int j = 0; j < 16; ++j) h[j] = b1[j];
    for (int k = 0; k < 41; ++k)
        for (int j = 0; j < 16; ++j) h[j] = fmaf(feats[k], W1[k * 16 + j], h[j]);
    for (int j = 0; j < 16; ++j) h[j] = h[j] > 0.f ? h[j] : __expf(h[j]) - 1.f;
    for (int j = 0; j < 16; ++j) gg[j] = b2[j];
    for (int k = 0; k < 16; ++k)
        for (int j = 0; j < 16; ++j) gg[j] = fmaf(h[k], W2[k * 16 + j], gg[j]);
    for (int j = 0; j < 16; ++j) gg[j] = gg[j] > 0.f ? gg[j] : __expf(gg[j]) - 1.f;
    for (int j = 0; j < 16; ++j) h[j] = b3[j];
    for (int k = 0; k < 16; ++k)
        for (int j = 0; j < 16; ++j) h[j] = fmaf(gg[k], W3[k * 16 + j], h[j]);
    for (int j = 0; j < 16; ++j) h[j] = h[j] > 0.f ? h[j] : __expf(h[j]) - 1.f;
    for (int j = 0; j < 16; ++j) gg[j] = b4[j];
    for (int k = 0; k < 16; ++k)
        for (int j = 0; j < 16; ++j) gg[j] = fmaf(h[k], W4[k * 16 + j], gg[j]);
    for (int j = 0; j < 16; ++j) gg[j] = gg[j] > 0.f ? gg[j] : __expf(gg[j]) - 1.f;
    float o = b5[0];
    for (int j = 0; j < 16; ++j) o = fmaf(gg[j], W5[j], o);
    out[i] = o;
}

extern "C" void kernel_launch(void* const* d_in, const int* in_sizes, int n_in,
                              void* d_out, int out_size, void* d_ws, size_t ws_size,
                              hipStream_t stream) {
    const float* x  = (const float*)d_in[0];
    const float* Bl = (const float*)d_in[1];
    const float* W1 = (const float*)d_in[2];
    const float* b1 = (const float*)d_in[3];
    const float* W2 = (const float*)d_in[4];
    const float* b2 = (const float*)d_in[5];
    const float* W3 = (const float*)d_in[6];
    const float* b3 = (const float*)d_in[7];
    const float* W4 = (const float*)d_in[8];
    const float* b4 = (const float*)d_in[9];
    const float* W5 = (const float*)d_in[10];
    const float* b5 = (const float*)d_in[11];
    float* out = (float*)d_out;

    const int N = out_size;
    const int NB = N / (128 * CH);
    const int rem = N - NB * (128 * CH);
    if (NB > 0)
        pixenc_mfma12<<<NB, 128, 0, stream>>>(x, Bl, W1, b1, W2, b2, W3, b3,
                                              W4, b4, W5, b5, out);
    if (rem > 0)
        pixenc_tail<<<(rem + 255) / 256, 256, 0, stream>>>(
            x, Bl, W1, b1, W2, b2, W3, b3, W4, b4, W5, b5, out, N, NB * 128 * CH);
}